// Round 1
// baseline (962.079 us; speedup 1.0000x reference)
//
#include <hip/hip_runtime.h>
#include <hip/hip_bf16.h>
#include <math.h>

// Shapes (fixed by the problem)
#define BATCH 2
#define SEQ   2048
#define NH    12
#define HD    64
#define EMB   768      // NH*HD
#define PLM   1280
#define FFN   640
#define MROWS (BATCH*SEQ)   // 4096

typedef __attribute__((ext_vector_type(8))) short short8;   // 8 bf16
typedef __attribute__((ext_vector_type(4))) float floatx4;

#define MFMA16(a,b,c) __builtin_amdgcn_mfma_f32_16x16x32_bf16((a),(b),(c),0,0,0)

static __device__ __forceinline__ float b2f(ushort u) {
    return __uint_as_float(((unsigned)u) << 16);
}
static __device__ __forceinline__ ushort f2b(float f) {
    unsigned x = __float_as_uint(f);
    unsigned r = (x + 0x7fffu + ((x >> 16) & 1u)) >> 16;   // RNE, finite inputs
    return (ushort)r;
}
// packed f32x2 -> bf16x2 (v_cvt_pk_bf16_f32)
static __device__ __forceinline__ ushort2 f2b2(float a, float b) {
    __hip_bfloat162 h = __float22bfloat162_rn(make_float2(a, b));
    union { __hip_bfloat162 h2; ushort2 u2; } c; c.h2 = h;
    return c.u2;
}

// ---------------------------------------------------------------------------
// Fused f32 -> bf16 conversion for all 8 inputs (dsts contiguous in ws).
// All segment vec4-counts are multiples of 256, so each block is uniform.
// ---------------------------------------------------------------------------
#define CV0 131072     // s_repre  (2*2048*128 /4)
#define CV1 1441792    // + plm    (2*2048*1280/4)
#define CV2 1687552    // + Wq     (768*1280/4)
#define CV3 1712128    // + Wk     (768*128/4)
#define CV4 1736704    // + Wv
#define CV5 1982464    // + Wo     (1280*768/4)
#define CV6 2187264    // + Wd     (640*1280/4)
#define CV7 2392064    // + Wu     (1280*640/4)

__global__ __launch_bounds__(256) void cvt_all(
    const float* __restrict__ s0, const float* __restrict__ s1,
    const float* __restrict__ s2, const float* __restrict__ s3,
    const float* __restrict__ s4, const float* __restrict__ s5,
    const float* __restrict__ s6, const float* __restrict__ s7,
    ushort* __restrict__ dst)
{
    int i = blockIdx.x * 256 + threadIdx.x;     // vec4 index
    const float* src; int start;
    if      (i < CV0) { src = s0; start = 0;   }
    else if (i < CV1) { src = s1; start = CV0; }
    else if (i < CV2) { src = s2; start = CV1; }
    else if (i < CV3) { src = s3; start = CV2; }
    else if (i < CV4) { src = s4; start = CV3; }
    else if (i < CV5) { src = s5; start = CV4; }
    else if (i < CV6) { src = s6; start = CV5; }
    else              { src = s7; start = CV6; }
    float4 v = ((const float4*)src)[i - start];
    ushort2 a = f2b2(v.x, v.y), b = f2b2(v.z, v.w);
    ushort4 o; o.x = a.x; o.y = a.y; o.z = b.x; o.w = b.y;
    ((ushort4*)dst)[i] = o;
}

// ---------------------------------------------------------------------------
// Generic NT GEMM: C[m,n] = sum_k A[m,k] * W[n,k]  (+ epilogue)
// A, W bf16; bias f32. Block tile 64x64, 4 waves; k unrolled by 64.
// EPI: 1 = bias + RoPE -> bf16 [B,H,S,D]
//      2 = bias -> bf16 transposed [B,H,D,S]  (staged via LDS, coalesced)
//      3 = bias + f32-residual add -> bf16 row-major
//      4 = bias + exact GELU -> bf16 row-major
//      5 = bias + bf16-residual add -> f32 row-major (final out)
// launch_bounds(256,4): cap 128 VGPR -> guaranteed 4 waves/SIMD for the
// latency-hungry 10-load : 8-MFMA inner loop (was (256,2) = 2 waves/SIMD).
// ---------------------------------------------------------------------------
template<int EPI>
__global__ __launch_bounds__(256, 4) void gemm_nt(
    const ushort* __restrict__ A,      // [M,K] bf16
    const ushort* __restrict__ W,      // [N,K] bf16
    const float*  __restrict__ bias,   // [N]   f32
    const float*  __restrict__ residF, // [M,N] f32  (EPI==3)
    const ushort* __restrict__ residB, // [M,N] bf16 (EPI==5)
    void* __restrict__ out_,
    int M, int N, int K)
{
    const int tid  = threadIdx.x;
    const int wave = tid >> 6;
    const int lane = tid & 63;
    const int quad = lane >> 4;
    const int col  = lane & 15;
    const int m0   = blockIdx.x * 64 + wave * 16;
    const int n0   = blockIdx.y * 64;

    const ushort* arow = A + (size_t)(m0 + col) * K + quad * 8;
    const ushort* wrow = W + (size_t)(n0 + col) * K + quad * 8;
    const size_t  wstep = (size_t)16 * K;

    const floatx4 zero = {0.f, 0.f, 0.f, 0.f};
    floatx4 acc[4] = {zero, zero, zero, zero};

    for (int k0 = 0; k0 < K; k0 += 64) {
        short8 a0 = *(const short8*)(arow + k0);
        short8 a1 = *(const short8*)(arow + k0 + 32);
        short8 b[8];
#pragma unroll
        for (int f = 0; f < 4; ++f) {
            b[2 * f]     = *(const short8*)(wrow + (size_t)f * wstep + k0);
            b[2 * f + 1] = *(const short8*)(wrow + (size_t)f * wstep + k0 + 32);
        }
#pragma unroll
        for (int f = 0; f < 4; ++f) {
            acc[f] = MFMA16(a0, b[2 * f], acc[f]);
            acc[f] = MFMA16(a1, b[2 * f + 1], acc[f]);
        }
    }

    float bs[4];
#pragma unroll
    for (int f = 0; f < 4; ++f) bs[f] = bias[n0 + f * 16 + col];

    if constexpr (EPI == 1) {
        ushort* out = (ushort*)out_;
        const int h = n0 >> 6;
#pragma unroll
        for (int r = 0; r < 4; ++r) {
            int m = m0 + quad * 4 + r;
            int b_ = m >> 11, s = m & (SEQ - 1);
            size_t obase = ((size_t)(b_ * NH + h) * SEQ + s) * HD;
#pragma unroll
            for (int f = 0; f < 2; ++f) {
                int d = f * 16 + col;                 // 0..31
                float x1 = acc[f][r] + bs[f];
                float x2 = acc[f + 2][r] + bs[f + 2];
                float invf = __expf((float)d * -0.2878231366242557f); // 10000^(-d/32)
                float theta = (float)s * invf;
                float sn, cs;
                sincosf(theta, &sn, &cs);
                out[obase + d]      = f2b(x1 * cs - x2 * sn);
                out[obase + d + 32] = f2b(x2 * cs + x1 * sn);
            }
        }
    } else if constexpr (EPI == 2) {
        // Transposed store [B,H,D,S]. Old path scattered 2B stores at 4KB
        // lane stride (~16x write amplification). Stage the 64x64 block tile
        // in LDS, then write 128B-contiguous rows along s.
        __shared__ __align__(16) ushort tile[64][72];   // +8 pad: bank spread
        ushort* out = (ushort*)out_;
        const int h = n0 >> 6;
        const int mi0 = wave * 16 + quad * 4;           // row within block tile
#pragma unroll
        for (int r = 0; r < 4; ++r)
#pragma unroll
            for (int f = 0; f < 4; ++f)
                tile[f * 16 + col][mi0 + r] = f2b(acc[f][r] + bs[f]);
        __syncthreads();
        const int mblk = blockIdx.x * 64;
        const int b_ = mblk >> 11, s0 = mblk & (SEQ - 1);
#pragma unroll
        for (int i = 0; i < 2; ++i) {
            int d = (tid >> 3) + i * 32;    // 0..63
            int c = (tid & 7) * 8;          // element offset along s
            short8 v = *(const short8*)&tile[d][c];
            *(short8*)&out[((size_t)((b_ * NH + h) * HD + d)) * SEQ + s0 + c] = v;
        }
    } else if constexpr (EPI == 3) {
        ushort* out = (ushort*)out_;
#pragma unroll
        for (int r = 0; r < 4; ++r) {
            int m = m0 + quad * 4 + r;
#pragma unroll
            for (int f = 0; f < 4; ++f) {
                size_t idx = (size_t)m * N + n0 + f * 16 + col;
                out[idx] = f2b(acc[f][r] + bs[f] + residF[idx]);
            }
        }
    } else if constexpr (EPI == 4) {
        ushort* out = (ushort*)out_;
#pragma unroll
        for (int r = 0; r < 4; ++r) {
            int m = m0 + quad * 4 + r;
#pragma unroll
            for (int f = 0; f < 4; ++f) {
                size_t idx = (size_t)m * N + n0 + f * 16 + col;
                float y = acc[f][r] + bs[f];
                out[idx] = f2b(0.5f * y * (1.0f + erff(y * 0.70710678118654752f)));
            }
        }
    } else {
        float* out = (float*)out_;
#pragma unroll
        for (int r = 0; r < 4; ++r) {
            int m = m0 + quad * 4 + r;
#pragma unroll
            for (int f = 0; f < 4; ++f) {
                size_t idx = (size_t)m * N + n0 + f * 16 + col;
                out[idx] = acc[f][r] + bs[f] + b2f(residB[idx]);
            }
        }
    }
}

// ---------------------------------------------------------------------------
// Attention v2: block = (qt, bh) with 16 q-rows; 4 waves split the 2048 kv
// into 512-col chunks. Grid 128 x 24 = 3072 blocks.
// Pass 1: partial exp-sums per wave, cross-wave reduce in LDS.
// Pass 2: recompute QK, write P f32 to padded LDS tile, coalesced float4
// copy to attn_out, PV MFMA from LDS A-frags; cross-wave PV reduce in LDS.
// launch_bounds(256,4): the previous (256,6) capped VGPRs at ~80 while the
// pass-2 live set is ~100 -> scratch spills in the hot loop. 128-reg cap
// removes spills; still 16 waves/CU (4 blocks/CU, LDS allows 9).
// ---------------------------------------------------------------------------
#define PSTRIDE 68   // 64 + 4 f32 pad: breaks power-of-2 bank stride

__global__ __launch_bounds__(256, 4) void attn_kernel(
    const ushort* __restrict__ qb, const ushort* __restrict__ kb,
    const ushort* __restrict__ vb,
    float* __restrict__ attn_out,    // [B,H,S,S] f32
    ushort* __restrict__ vals)       // [B*S, EMB] bf16
{
    const int qt   = blockIdx.x;     // 0..127 (16 q-rows)
    const int bh   = blockIdx.y;     // 0..23
    const int tid  = threadIdx.x;
    const int wave = tid >> 6;
    const int lane = tid & 63;
    const int quad = lane >> 4;
    const int col  = lane & 15;
    const int kv0  = wave * 512;
    const int qrow0 = qt * 16;

    __shared__ __align__(16) float P32[4][16 * PSTRIDE];  // per-wave tiles
    __shared__ float SS[4][16];

    const floatx4 zero = {0.f, 0.f, 0.f, 0.f};

    // Q fragments for the block's 16 rows (same for all waves; L1-served)
    const ushort* qrow = qb + ((size_t)bh * SEQ + qrow0 + col) * HD + quad * 8;
    short8 aq0 = *(const short8*)qrow;
    short8 aq1 = *(const short8*)(qrow + 32);

    const ushort* kbase = kb + (size_t)bh * SEQ * HD + (size_t)(kv0 + col) * HD + quad * 8;
    const ushort* vbase = vb + (size_t)bh * HD * SEQ + (size_t)col * SEQ + kv0 + quad * 8;

    // ---- pass 1: partial row sums of exp over this wave's 512 kv ----
    float sums[4] = {0.f, 0.f, 0.f, 0.f};
    for (int ch = 0; ch < 8; ++ch) {
#pragma unroll
        for (int f = 0; f < 4; ++f) {
            const ushort* kr = kbase + (size_t)(ch * 64 + f * 16) * HD;
            short8 b0 = *(const short8*)kr;
            short8 b1 = *(const short8*)(kr + 32);
            floatx4 t = MFMA16(aq0, b0, zero);
            t = MFMA16(aq1, b1, t);
#pragma unroll
            for (int r = 0; r < 4; ++r) sums[r] += __expf(t[r] * 0.125f);
        }
    }
#pragma unroll
    for (int r = 0; r < 4; ++r) {
        float v = sums[r];
        v += __shfl_xor(v, 1); v += __shfl_xor(v, 2);
        v += __shfl_xor(v, 4); v += __shfl_xor(v, 8);
        sums[r] = v;
    }
    if (col == 0) {
#pragma unroll
        for (int r = 0; r < 4; ++r) SS[wave][quad * 4 + r] = sums[r];
    }
    __syncthreads();
    float rinv[4];
#pragma unroll
    for (int r = 0; r < 4; ++r) {
        int row = quad * 4 + r;
        rinv[r] = 1.0f / (SS[0][row] + SS[1][row] + SS[2][row] + SS[3][row]);
    }

    // ---- pass 2: P write (LDS -> coalesced global) + PV ----
    const size_t gbase = (size_t)bh * SEQ + qrow0;
    floatx4 acco[4] = {zero, zero, zero, zero};
    for (int ch = 0; ch < 8; ++ch) {
#pragma unroll
        for (int f = 0; f < 4; ++f) {
            const ushort* kr = kbase + (size_t)(ch * 64 + f * 16) * HD;
            short8 b0 = *(const short8*)kr;
            short8 b1 = *(const short8*)(kr + 32);
            floatx4 t = MFMA16(aq0, b0, zero);
            t = MFMA16(aq1, b1, t);
#pragma unroll
            for (int r = 0; r < 4; ++r) {
                float p = __expf(t[r] * 0.125f) * rinv[r];
                P32[wave][(quad * 4 + r) * PSTRIDE + f * 16 + col] = p;
            }
        }
        // coalesced copy: 4 iters x (4 rows x 256 B contiguous)
#pragma unroll
        for (int it = 0; it < 4; ++it) {
            int row = it * 4 + quad;
            float4 v = *(const float4*)&P32[wave][row * PSTRIDE + col * 4];
            *(float4*)&attn_out[(gbase + row) * SEQ + kv0 + ch * 64 + col * 4] = v;
        }
        // PV: A-frags from LDS (f32 -> packed bf16 cvt)
        const float* pl = &P32[wave][col * PSTRIDE + quad * 8];
        float4 pa = *(const float4*)pl;
        float4 pb = *(const float4*)(pl + 4);
        float4 pc = *(const float4*)(pl + 32);
        float4 pd = *(const float4*)(pl + 36);
        ushort2 c0 = f2b2(pa.x, pa.y), c1 = f2b2(pa.z, pa.w);
        ushort2 c2 = f2b2(pb.x, pb.y), c3 = f2b2(pb.z, pb.w);
        ushort2 c4 = f2b2(pc.x, pc.y), c5 = f2b2(pc.z, pc.w);
        ushort2 c6 = f2b2(pd.x, pd.y), c7 = f2b2(pd.z, pd.w);
        short8 ap0 = {(short)c0.x, (short)c0.y, (short)c1.x, (short)c1.y,
                      (short)c2.x, (short)c2.y, (short)c3.x, (short)c3.y};
        short8 ap1 = {(short)c4.x, (short)c4.y, (short)c5.x, (short)c5.y,
                      (short)c6.x, (short)c6.y, (short)c7.x, (short)c7.y};
#pragma unroll
        for (int f = 0; f < 4; ++f) {
            const ushort* vr = vbase + (size_t)(f * 16) * SEQ + ch * 64;
            short8 b0 = *(const short8*)vr;
            short8 b1 = *(const short8*)(vr + 32);
            acco[f] = MFMA16(ap0, b0, acco[f]);
            acco[f] = MFMA16(ap1, b1, acco[f]);
        }
    }

    // ---- cross-wave PV reduction via LDS (reuse P32) ----
    __syncthreads();   // everyone done with pass-2 tiles
#pragma unroll
    for (int f = 0; f < 4; ++f)
#pragma unroll
        for (int r = 0; r < 4; ++r)
            P32[wave][(quad * 4 + r) * PSTRIDE + f * 16 + col] = acco[f][r];
    __syncthreads();

    {
        int row = tid >> 4;            // 0..15
        int d0  = (tid & 15) * 4;      // 0..60
        int off = row * PSTRIDE + d0;
        float4 s0 = *(const float4*)&P32[0][off];
        float4 s1 = *(const float4*)&P32[1][off];
        float4 s2 = *(const float4*)&P32[2][off];
        float4 s3 = *(const float4*)&P32[3][off];
        float4 s;
        s.x = s0.x + s1.x + s2.x + s3.x;
        s.y = s0.y + s1.y + s2.y + s3.y;
        s.z = s0.z + s1.z + s2.z + s3.z;
        s.w = s0.w + s1.w + s2.w + s3.w;
        ushort2 u0 = f2b2(s.x, s.y), u1 = f2b2(s.z, s.w);
        ushort4 o; o.x = u0.x; o.y = u0.y; o.z = u1.x; o.w = u1.y;
        const int b = bh / NH, h = bh - b * NH;
        size_t idx = ((size_t)(b * SEQ + qrow0 + row)) * EMB + h * HD + d0;
        *(ushort4*)&vals[idx] = o;
    }
}

// ---------------------------------------------------------------------------
// LayerNorm over 1280, one block (256 threads) per row.
// ---------------------------------------------------------------------------
__global__ __launch_bounds__(256) void ln_kernel(
    const ushort* __restrict__ x, const float* __restrict__ g,
    const float* __restrict__ bt, ushort* __restrict__ out)
{
    const int row = blockIdx.x;
    const int tid = threadIdx.x;
    const ushort* xr = x + (size_t)row * PLM;

    float xs[5];
    float s = 0.f, s2 = 0.f;
#pragma unroll
    for (int i = 0; i < 5; ++i) {
        float v = b2f(xr[tid + i * 256]);
        xs[i] = v; s += v; s2 += v * v;
    }
#pragma unroll
    for (int off = 1; off < 64; off <<= 1) {
        s  += __shfl_xor(s,  off);
        s2 += __shfl_xor(s2, off);
    }
    __shared__ float red[8];
    const int wave = tid >> 6, lane = tid & 63;
    if (lane == 0) { red[wave] = s; red[4 + wave] = s2; }
    __syncthreads();
    s  = red[0] + red[1] + red[2] + red[3];
    s2 = red[4] + red[5] + red[6] + red[7];
    float mean = s * (1.0f / PLM);
    float var  = s2 * (1.0f / PLM) - mean * mean;
    float rstd = rsqrtf(var + 1e-5f);

    ushort* orow = out + (size_t)row * PLM;
#pragma unroll
    for (int i = 0; i < 5; ++i) {
        int c = tid + i * 256;
        orow[c] = f2b((xs[i] - mean) * rstd * g[c] + bt[c]);
    }
}

// ---------------------------------------------------------------------------
extern "C" void kernel_launch(void* const* d_in, const int* in_sizes, int n_in,
                              void* d_out, int out_size, void* d_ws, size_t ws_size,
                              hipStream_t stream)
{
    const float* s_repre = (const float*)d_in[0];
    const float* plm     = (const float*)d_in[1];
    const float* Wq = (const float*)d_in[2];
    const float* bq = (const float*)d_in[3];
    const float* Wk = (const float*)d_in[4];
    const float* bk = (const float*)d_in[5];
    const float* Wv = (const float*)d_in[6];
    const float* bv = (const float*)d_in[7];
    const float* Wo = (const float*)d_in[8];
    const float* bo = (const float*)d_in[9];
    const float* ln_g = (const float*)d_in[10];
    const float* ln_b = (const float*)d_in[11];
    const float* Wd = (const float*)d_in[12];
    const float* bd = (const float*)d_in[13];
    const float* Wu = (const float*)d_in[14];
    const float* bu = (const float*)d_in[15];

    // workspace layout (bf16 elements)
    ushort* ws    = (ushort*)d_ws;
    ushort* q_buf = ws;                          // [B,H,S,D]
    ushort* k_buf = q_buf + (size_t)MROWS * EMB;
    ushort* v_buf = k_buf + (size_t)MROWS * EMB; // [B,H,D,S]
    ushort* vals  = v_buf + (size_t)MROWS * EMB; // [B*S, EMB]
    ushort* x_buf = vals  + (size_t)MROWS * EMB; // [B*S, PLM]
    ushort* resid = x_buf + (size_t)MROWS * PLM; // [B*S, PLM]
    ushort* h_buf = resid + (size_t)MROWS * PLM; // [B*S, FFN]
    // bf16 copies of f32 inputs — contiguous, in cvt_all segment order
    ushort* sr_b  = h_buf + (size_t)MROWS * FFN;
    ushort* plm_b = sr_b  + (size_t)MROWS * 128;
    ushort* Wq_b  = plm_b + (size_t)MROWS * PLM;
    ushort* Wk_b  = Wq_b  + (size_t)EMB * PLM;
    ushort* Wv_b  = Wk_b  + (size_t)EMB * 128;
    ushort* Wo_b  = Wv_b  + (size_t)EMB * 128;
    ushort* Wd_b  = Wo_b  + (size_t)PLM * EMB;
    ushort* Wu_b  = Wd_b  + (size_t)FFN * PLM;

    float* out_main = (float*)d_out;                        // [B*S, PLM]
    float* attn_out = out_main + (size_t)MROWS * PLM;       // [B,H,S,S]

    dim3 blk(256);

    // one fused conversion pass over all f32 inputs
    cvt_all<<<dim3(CV7 / 256), blk, 0, stream>>>(
        s_repre, plm, Wq, Wk, Wv, Wo, Wd, Wu, sr_b);

    // q = RoPE(plm @ Wq^T + bq)            -> [B,H,S,D]
    gemm_nt<1><<<dim3(MROWS / 64, EMB / 64), blk, 0, stream>>>(
        plm_b, Wq_b, bq, nullptr, nullptr, q_buf, MROWS, EMB, PLM);
    // k = RoPE(s_repre @ Wk^T + bk)        -> [B,H,S,D]
    gemm_nt<1><<<dim3(MROWS / 64, EMB / 64), blk, 0, stream>>>(
        sr_b, Wk_b, bk, nullptr, nullptr, k_buf, MROWS, EMB, 128);
    // v = s_repre @ Wv^T + bv              -> [B,H,D,S]
    gemm_nt<2><<<dim3(MROWS / 64, EMB / 64), blk, 0, stream>>>(
        sr_b, Wv_b, bv, nullptr, nullptr, v_buf, MROWS, EMB, 128);

    // attention probs (f32, to d_out) + vals (bf16)
    attn_kernel<<<dim3(SEQ / 16, BATCH * NH), blk, 0, stream>>>(
        q_buf, k_buf, v_buf, attn_out, vals);

    // x = vals @ Wo^T + bo + plm           -> x_buf (bf16)
    gemm_nt<3><<<dim3(MROWS / 64, PLM / 64), blk, 0, stream>>>(
        vals, Wo_b, bo, plm, nullptr, x_buf, MROWS, PLM, EMB);

    // resid = LayerNorm(x)
    ln_kernel<<<dim3(MROWS), blk, 0, stream>>>(x_buf, ln_g, ln_b, resid);

    // h = gelu(resid @ Wd^T + bd)
    gemm_nt<4><<<dim3(MROWS / 64, FFN / 64), blk, 0, stream>>>(
        resid, Wd_b, bd, nullptr, nullptr, h_buf, MROWS, FFN, PLM);

    // out = h @ Wu^T + bu + resid          -> d_out (f32)
    gemm_nt<5><<<dim3(MROWS / 64, PLM / 64), blk, 0, stream>>>(
        h_buf, Wu_b, bu, nullptr, resid, out_main, MROWS, PLM, FFN);
}

// Round 2
// 781.257 us; speedup vs baseline: 1.2314x; 1.2314x over previous
//
#include <hip/hip_runtime.h>
#include <hip/hip_bf16.h>
#include <math.h>

// Shapes (fixed by the problem)
#define BATCH 2
#define SEQ   2048
#define NH    12
#define HD    64
#define EMB   768      // NH*HD
#define PLM   1280
#define FFN   640
#define MROWS (BATCH*SEQ)   // 4096

typedef __attribute__((ext_vector_type(8))) short short8;   // 8 bf16
typedef __attribute__((ext_vector_type(4))) float floatx4;

#define MFMA16(a,b,c) __builtin_amdgcn_mfma_f32_16x16x32_bf16((a),(b),(c),0,0,0)

static __device__ __forceinline__ float b2f(ushort u) {
    return __uint_as_float(((unsigned)u) << 16);
}
static __device__ __forceinline__ ushort f2b(float f) {
    unsigned x = __float_as_uint(f);
    unsigned r = (x + 0x7fffu + ((x >> 16) & 1u)) >> 16;   // RNE, finite inputs
    return (ushort)r;
}
// packed f32x2 -> bf16x2 (v_cvt_pk_bf16_f32)
static __device__ __forceinline__ ushort2 f2b2(float a, float b) {
    __hip_bfloat162 h = __float22bfloat162_rn(make_float2(a, b));
    union { __hip_bfloat162 h2; ushort2 u2; } c; c.h2 = h;
    return c.u2;
}

// ---------------------------------------------------------------------------
// Fused f32 -> bf16 conversion for all 8 inputs (dsts contiguous in ws).
// ---------------------------------------------------------------------------
#define CV0 131072     // s_repre  (2*2048*128 /4)
#define CV1 1441792    // + plm    (2*2048*1280/4)
#define CV2 1687552    // + Wq     (768*1280/4)
#define CV3 1712128    // + Wk     (768*128/4)
#define CV4 1736704    // + Wv
#define CV5 1982464    // + Wo     (1280*768/4)
#define CV6 2187264    // + Wd     (640*1280/4)
#define CV7 2392064    // + Wu     (1280*640/4)

__global__ __launch_bounds__(256) void cvt_all(
    const float* __restrict__ s0, const float* __restrict__ s1,
    const float* __restrict__ s2, const float* __restrict__ s3,
    const float* __restrict__ s4, const float* __restrict__ s5,
    const float* __restrict__ s6, const float* __restrict__ s7,
    ushort* __restrict__ dst)
{
    int i = blockIdx.x * 256 + threadIdx.x;     // vec4 index
    const float* src; int start;
    if      (i < CV0) { src = s0; start = 0;   }
    else if (i < CV1) { src = s1; start = CV0; }
    else if (i < CV2) { src = s2; start = CV1; }
    else if (i < CV3) { src = s3; start = CV2; }
    else if (i < CV4) { src = s4; start = CV3; }
    else if (i < CV5) { src = s5; start = CV4; }
    else if (i < CV6) { src = s6; start = CV5; }
    else              { src = s7; start = CV6; }
    float4 v = ((const float4*)src)[i - start];
    ushort2 a = f2b2(v.x, v.y), b = f2b2(v.z, v.w);
    ushort4 o; o.x = a.x; o.y = a.y; o.z = b.x; o.w = b.y;
    ((ushort4*)dst)[i] = o;
}

// ---------------------------------------------------------------------------
// Stage one 64-row x 128-byte (64 bf16) tile from global into LDS via
// global_load_lds (width 16). LDS layout is linear [row][128B] with the
// T2 XOR-swizzle realized by PRE-SWIZZLING the global source column:
//   LDS[row*128 + c] = G[row][c ^ ((row&7)<<4)]
// (gload_lds dest must be linear: wave-uniform base + lane*16; m104/m173.)
// 256 threads, 2 segments each (512 x 16 B = 8 KB).
// ---------------------------------------------------------------------------
static __device__ __forceinline__ void stage_tile(
    const ushort* __restrict__ g,   // global tile base (row 0, k-col 0)
    int strideBytes,                // global row stride in bytes (K*2)
    int tid, ushort* lds)
{
    const int l   = tid & 63;
    const int w   = tid >> 6;
    const int sub = l >> 3;                             // row&7
    const int scol = (((l & 7) << 4) ^ (sub << 4));     // pre-swizzled col byte
#pragma unroll
    for (int s = 0; s < 2; ++s) {
        const int row = s * 32 + w * 8 + sub;
        const char* gp = (const char*)g + (size_t)row * strideBytes + scol;
        char* lp = (char*)lds + s * 4096 + w * 1024;    // wave-uniform base
        __builtin_amdgcn_global_load_lds(
            (const __attribute__((address_space(1))) void*)gp,
            (__attribute__((address_space(3))) void*)lp, 16, 0, 0);
    }
}

// ---------------------------------------------------------------------------
// NT GEMM: C[m,n] = sum_k A[m,k] * W[n,k]  (+ epilogue)
// 2-phase pipelined: double-buffered LDS tiles (A,B 64x64 bf16), staged by
// global_load_lds w16 with pre-swizzled source (bank-conflict-free ds_read).
// Per k-step: STAGE(next) -> ds_read frags(cur) -> 8 MFMA -> barrier.
// Wave w computes rows m0=bx*64+w*16 x all 64 cols (same mapping/epilogues
// as the previous direct-global version).
// EPI: 1=bias+RoPE->bf16 [B,H,S,D]; 2=bias->bf16 [B,H,D,S] (LDS transpose);
//      3=bias+f32 resid->bf16; 4=bias+GELU->bf16; 5=bias+bf16 resid->f32
// ---------------------------------------------------------------------------
template<int EPI>
__global__ __launch_bounds__(256, 4) void gemm_nt(
    const ushort* __restrict__ A,      // [M,K] bf16
    const ushort* __restrict__ W,      // [N,K] bf16
    const float*  __restrict__ bias,   // [N]   f32
    const float*  __restrict__ residF, // [M,N] f32  (EPI==3)
    const ushort* __restrict__ residB, // [M,N] bf16 (EPI==5)
    void* __restrict__ out_,
    int M, int N, int K)
{
    __shared__ __align__(16) ushort As[2][64 * 64];
    __shared__ __align__(16) ushort Bs[2][64 * 64];

    const int tid  = threadIdx.x;
    const int wave = tid >> 6;
    const int lane = tid & 63;
    const int quad = lane >> 4;
    const int col  = lane & 15;
    const int m0   = blockIdx.x * 64 + wave * 16;
    const int n0   = blockIdx.y * 64;

    const int strideBytes = K * 2;
    const ushort* Ag = A + (size_t)(blockIdx.x * 64) * K;
    const ushort* Wg = W + (size_t)n0 * K;

    // swizzled frag-read byte offsets within a tile
    const int sw = (col & 7) << 4;
    const int a_off0 = (wave * 16 + col) * 128 + ((quad * 16) ^ sw);
    const int a_off1 = (wave * 16 + col) * 128 + ((64 + quad * 16) ^ sw);
    int b_off[8];
#pragma unroll
    for (int f = 0; f < 4; ++f) {
        int rb = (f * 16 + col) * 128;
        b_off[2 * f]     = rb + ((quad * 16) ^ sw);
        b_off[2 * f + 1] = rb + ((64 + quad * 16) ^ sw);
    }

    const floatx4 zero = {0.f, 0.f, 0.f, 0.f};
    floatx4 acc[4] = {zero, zero, zero, zero};

    // prologue: stage first K-tile
    stage_tile(Ag, strideBytes, tid, As[0]);
    stage_tile(Wg, strideBytes, tid, Bs[0]);
    __syncthreads();   // implicit vmcnt(0) drain before barrier

    int buf = 0;
    for (int k0 = 0; k0 < K; k0 += 64) {
        if (k0 + 64 < K) {   // issue next-tile loads BEFORE compute (2-phase)
            stage_tile(Ag + (k0 + 64), strideBytes, tid, As[buf ^ 1]);
            stage_tile(Wg + (k0 + 64), strideBytes, tid, Bs[buf ^ 1]);
        }
        const char* Ab = (const char*)&As[buf][0];
        const char* Bb = (const char*)&Bs[buf][0];
        short8 a0 = *(const short8*)(Ab + a_off0);
        short8 a1 = *(const short8*)(Ab + a_off1);
        short8 b[8];
#pragma unroll
        for (int f = 0; f < 8; ++f) b[f] = *(const short8*)(Bb + b_off[f]);
#pragma unroll
        for (int f = 0; f < 4; ++f) {
            acc[f] = MFMA16(a0, b[2 * f], acc[f]);
            acc[f] = MFMA16(a1, b[2 * f + 1], acc[f]);
        }
        __syncthreads();   // drains vmcnt (stage done) + all reads of buf done
        buf ^= 1;
    }

    float bs[4];
#pragma unroll
    for (int f = 0; f < 4; ++f) bs[f] = bias[n0 + f * 16 + col];

    if constexpr (EPI == 1) {
        ushort* out = (ushort*)out_;
        const int h = n0 >> 6;
#pragma unroll
        for (int r = 0; r < 4; ++r) {
            int m = m0 + quad * 4 + r;
            int b_ = m >> 11, s = m & (SEQ - 1);
            size_t obase = ((size_t)(b_ * NH + h) * SEQ + s) * HD;
#pragma unroll
            for (int f = 0; f < 2; ++f) {
                int d = f * 16 + col;                 // 0..31
                float x1 = acc[f][r] + bs[f];
                float x2 = acc[f + 2][r] + bs[f + 2];
                float invf = __expf((float)d * -0.2878231366242557f); // 10000^(-d/32)
                float theta = (float)s * invf;
                float sn, cs;
                sincosf(theta, &sn, &cs);
                out[obase + d]      = f2b(x1 * cs - x2 * sn);
                out[obase + d + 32] = f2b(x2 * cs + x1 * sn);
            }
        }
    } else if constexpr (EPI == 2) {
        // Transposed store [B,H,D,S]: stage block tile in LDS (reuse As,
        // 16 KB >= 64*72*2 B), then 128B-contiguous stores along s.
        ushort (*tile)[72] = (ushort (*)[72])&As[0][0];
        ushort* out = (ushort*)out_;
        const int h = n0 >> 6;
        const int mi0 = wave * 16 + quad * 4;           // row within block tile
#pragma unroll
        for (int r = 0; r < 4; ++r)
#pragma unroll
            for (int f = 0; f < 4; ++f)
                tile[f * 16 + col][mi0 + r] = f2b(acc[f][r] + bs[f]);
        __syncthreads();
        const int mblk = blockIdx.x * 64;
        const int b_ = mblk >> 11, s0 = mblk & (SEQ - 1);
#pragma unroll
        for (int i = 0; i < 2; ++i) {
            int d = (tid >> 3) + i * 32;    // 0..63
            int c = (tid & 7) * 8;          // element offset along s
            short8 v = *(const short8*)&tile[d][c];
            *(short8*)&out[((size_t)((b_ * NH + h) * HD + d)) * SEQ + s0 + c] = v;
        }
    } else if constexpr (EPI == 3) {
        ushort* out = (ushort*)out_;
#pragma unroll
        for (int r = 0; r < 4; ++r) {
            int m = m0 + quad * 4 + r;
#pragma unroll
            for (int f = 0; f < 4; ++f) {
                size_t idx = (size_t)m * N + n0 + f * 16 + col;
                out[idx] = f2b(acc[f][r] + bs[f] + residF[idx]);
            }
        }
    } else if constexpr (EPI == 4) {
        ushort* out = (ushort*)out_;
#pragma unroll
        for (int r = 0; r < 4; ++r) {
            int m = m0 + quad * 4 + r;
#pragma unroll
            for (int f = 0; f < 4; ++f) {
                size_t idx = (size_t)m * N + n0 + f * 16 + col;
                float y = acc[f][r] + bs[f];
                out[idx] = f2b(0.5f * y * (1.0f + erff(y * 0.70710678118654752f)));
            }
        }
    } else {
        float* out = (float*)out_;
#pragma unroll
        for (int r = 0; r < 4; ++r) {
            int m = m0 + quad * 4 + r;
#pragma unroll
            for (int f = 0; f < 4; ++f) {
                size_t idx = (size_t)m * N + n0 + f * 16 + col;
                out[idx] = acc[f][r] + bs[f] + b2f(residB[idx]);
            }
        }
    }
}

// ---------------------------------------------------------------------------
// Attention v2 (unchanged this round): block = (qt, bh) with 16 q-rows;
// 4 waves split the 2048 kv into 512-col chunks.
// ---------------------------------------------------------------------------
#define PSTRIDE 68   // 64 + 4 f32 pad: breaks power-of-2 bank stride

__global__ __launch_bounds__(256, 4) void attn_kernel(
    const ushort* __restrict__ qb, const ushort* __restrict__ kb,
    const ushort* __restrict__ vb,
    float* __restrict__ attn_out,    // [B,H,S,S] f32
    ushort* __restrict__ vals)       // [B*S, EMB] bf16
{
    const int qt   = blockIdx.x;     // 0..127 (16 q-rows)
    const int bh   = blockIdx.y;     // 0..23
    const int tid  = threadIdx.x;
    const int wave = tid >> 6;
    const int lane = tid & 63;
    const int quad = lane >> 4;
    const int col  = lane & 15;
    const int kv0  = wave * 512;
    const int qrow0 = qt * 16;

    __shared__ __align__(16) float P32[4][16 * PSTRIDE];  // per-wave tiles
    __shared__ float SS[4][16];

    const floatx4 zero = {0.f, 0.f, 0.f, 0.f};

    const ushort* qrow = qb + ((size_t)bh * SEQ + qrow0 + col) * HD + quad * 8;
    short8 aq0 = *(const short8*)qrow;
    short8 aq1 = *(const short8*)(qrow + 32);

    const ushort* kbase = kb + (size_t)bh * SEQ * HD + (size_t)(kv0 + col) * HD + quad * 8;
    const ushort* vbase = vb + (size_t)bh * HD * SEQ + (size_t)col * SEQ + kv0 + quad * 8;

    // ---- pass 1: partial row sums of exp over this wave's 512 kv ----
    float sums[4] = {0.f, 0.f, 0.f, 0.f};
    for (int ch = 0; ch < 8; ++ch) {
#pragma unroll
        for (int f = 0; f < 4; ++f) {
            const ushort* kr = kbase + (size_t)(ch * 64 + f * 16) * HD;
            short8 b0 = *(const short8*)kr;
            short8 b1 = *(const short8*)(kr + 32);
            floatx4 t = MFMA16(aq0, b0, zero);
            t = MFMA16(aq1, b1, t);
#pragma unroll
            for (int r = 0; r < 4; ++r) sums[r] += __expf(t[r] * 0.125f);
        }
    }
#pragma unroll
    for (int r = 0; r < 4; ++r) {
        float v = sums[r];
        v += __shfl_xor(v, 1); v += __shfl_xor(v, 2);
        v += __shfl_xor(v, 4); v += __shfl_xor(v, 8);
        sums[r] = v;
    }
    if (col == 0) {
#pragma unroll
        for (int r = 0; r < 4; ++r) SS[wave][quad * 4 + r] = sums[r];
    }
    __syncthreads();
    float rinv[4];
#pragma unroll
    for (int r = 0; r < 4; ++r) {
        int row = quad * 4 + r;
        rinv[r] = 1.0f / (SS[0][row] + SS[1][row] + SS[2][row] + SS[3][row]);
    }

    // ---- pass 2: P write (LDS -> coalesced global) + PV ----
    const size_t gbase = (size_t)bh * SEQ + qrow0;
    floatx4 acco[4] = {zero, zero, zero, zero};
    for (int ch = 0; ch < 8; ++ch) {
#pragma unroll
        for (int f = 0; f < 4; ++f) {
            const ushort* kr = kbase + (size_t)(ch * 64 + f * 16) * HD;
            short8 b0 = *(const short8*)kr;
            short8 b1 = *(const short8*)(kr + 32);
            floatx4 t = MFMA16(aq0, b0, zero);
            t = MFMA16(aq1, b1, t);
#pragma unroll
            for (int r = 0; r < 4; ++r) {
                float p = __expf(t[r] * 0.125f) * rinv[r];
                P32[wave][(quad * 4 + r) * PSTRIDE + f * 16 + col] = p;
            }
        }
        // coalesced copy: 4 iters x (4 rows x 256 B contiguous)
#pragma unroll
        for (int it = 0; it < 4; ++it) {
            int row = it * 4 + quad;
            float4 v = *(const float4*)&P32[wave][row * PSTRIDE + col * 4];
            *(float4*)&attn_out[(gbase + row) * SEQ + kv0 + ch * 64 + col * 4] = v;
        }
        // PV: A-frags from LDS (f32 -> packed bf16 cvt)
        const float* pl = &P32[wave][col * PSTRIDE + quad * 8];
        float4 pa = *(const float4*)pl;
        float4 pb = *(const float4*)(pl + 4);
        float4 pc = *(const float4*)(pl + 32);
        float4 pd = *(const float4*)(pl + 36);
        ushort2 c0 = f2b2(pa.x, pa.y), c1 = f2b2(pa.z, pa.w);
        ushort2 c2 = f2b2(pb.x, pb.y), c3 = f2b2(pb.z, pb.w);
        ushort2 c4 = f2b2(pc.x, pc.y), c5 = f2b2(pc.z, pc.w);
        ushort2 c6 = f2b2(pd.x, pd.y), c7 = f2b2(pd.z, pd.w);
        short8 ap0 = {(short)c0.x, (short)c0.y, (short)c1.x, (short)c1.y,
                      (short)c2.x, (short)c2.y, (short)c3.x, (short)c3.y};
        short8 ap1 = {(short)c4.x, (short)c4.y, (short)c5.x, (short)c5.y,
                      (short)c6.x, (short)c6.y, (short)c7.x, (short)c7.y};
#pragma unroll
        for (int f = 0; f < 4; ++f) {
            const ushort* vr = vbase + (size_t)(f * 16) * SEQ + ch * 64;
            short8 b0 = *(const short8*)vr;
            short8 b1 = *(const short8*)(vr + 32);
            acco[f] = MFMA16(ap0, b0, acco[f]);
            acco[f] = MFMA16(ap1, b1, acco[f]);
        }
    }

    // ---- cross-wave PV reduction via LDS (reuse P32) ----
    __syncthreads();   // everyone done with pass-2 tiles
#pragma unroll
    for (int f = 0; f < 4; ++f)
#pragma unroll
        for (int r = 0; r < 4; ++r)
            P32[wave][(quad * 4 + r) * PSTRIDE + f * 16 + col] = acco[f][r];
    __syncthreads();

    {
        int row = tid >> 4;            // 0..15
        int d0  = (tid & 15) * 4;      // 0..60
        int off = row * PSTRIDE + d0;
        float4 s0 = *(const float4*)&P32[0][off];
        float4 s1 = *(const float4*)&P32[1][off];
        float4 s2 = *(const float4*)&P32[2][off];
        float4 s3 = *(const float4*)&P32[3][off];
        float4 s;
        s.x = s0.x + s1.x + s2.x + s3.x;
        s.y = s0.y + s1.y + s2.y + s3.y;
        s.z = s0.z + s1.z + s2.z + s3.z;
        s.w = s0.w + s1.w + s2.w + s3.w;
        ushort2 u0 = f2b2(s.x, s.y), u1 = f2b2(s.z, s.w);
        ushort4 o; o.x = u0.x; o.y = u0.y; o.z = u1.x; o.w = u1.y;
        const int b = bh / NH, h = bh - b * NH;
        size_t idx = ((size_t)(b * SEQ + qrow0 + row)) * EMB + h * HD + d0;
        *(ushort4*)&vals[idx] = o;
    }
}

// ---------------------------------------------------------------------------
// LayerNorm over 1280, one block (256 threads) per row.
// ---------------------------------------------------------------------------
__global__ __launch_bounds__(256) void ln_kernel(
    const ushort* __restrict__ x, const float* __restrict__ g,
    const float* __restrict__ bt, ushort* __restrict__ out)
{
    const int row = blockIdx.x;
    const int tid = threadIdx.x;
    const ushort* xr = x + (size_t)row * PLM;

    float xs[5];
    float s = 0.f, s2 = 0.f;
#pragma unroll
    for (int i = 0; i < 5; ++i) {
        float v = b2f(xr[tid + i * 256]);
        xs[i] = v; s += v; s2 += v * v;
    }
#pragma unroll
    for (int off = 1; off < 64; off <<= 1) {
        s  += __shfl_xor(s,  off);
        s2 += __shfl_xor(s2, off);
    }
    __shared__ float red[8];
    const int wave = tid >> 6, lane = tid & 63;
    if (lane == 0) { red[wave] = s; red[4 + wave] = s2; }
    __syncthreads();
    s  = red[0] + red[1] + red[2] + red[3];
    s2 = red[4] + red[5] + red[6] + red[7];
    float mean = s * (1.0f / PLM);
    float var  = s2 * (1.0f / PLM) - mean * mean;
    float rstd = rsqrtf(var + 1e-5f);

    ushort* orow = out + (size_t)row * PLM;
#pragma unroll
    for (int i = 0; i < 5; ++i) {
        int c = tid + i * 256;
        orow[c] = f2b((xs[i] - mean) * rstd * g[c] + bt[c]);
    }
}

// ---------------------------------------------------------------------------
extern "C" void kernel_launch(void* const* d_in, const int* in_sizes, int n_in,
                              void* d_out, int out_size, void* d_ws, size_t ws_size,
                              hipStream_t stream)
{
    const float* s_repre = (const float*)d_in[0];
    const float* plm     = (const float*)d_in[1];
    const float* Wq = (const float*)d_in[2];
    const float* bq = (const float*)d_in[3];
    const float* Wk = (const float*)d_in[4];
    const float* bk = (const float*)d_in[5];
    const float* Wv = (const float*)d_in[6];
    const float* bv = (const float*)d_in[7];
    const float* Wo = (const float*)d_in[8];
    const float* bo = (const float*)d_in[9];
    const float* ln_g = (const float*)d_in[10];
    const float* ln_b = (const float*)d_in[11];
    const float* Wd = (const float*)d_in[12];
    const float* bd = (const float*)d_in[13];
    const float* Wu = (const float*)d_in[14];
    const float* bu = (const float*)d_in[15];

    // workspace layout (bf16 elements)
    ushort* ws    = (ushort*)d_ws;
    ushort* q_buf = ws;                          // [B,H,S,D]
    ushort* k_buf = q_buf + (size_t)MROWS * EMB;
    ushort* v_buf = k_buf + (size_t)MROWS * EMB; // [B,H,D,S]
    ushort* vals  = v_buf + (size_t)MROWS * EMB; // [B*S, EMB]
    ushort* x_buf = vals  + (size_t)MROWS * EMB; // [B*S, PLM]
    ushort* resid = x_buf + (size_t)MROWS * PLM; // [B*S, PLM]
    ushort* h_buf = resid + (size_t)MROWS * PLM; // [B*S, FFN]
    // bf16 copies of f32 inputs — contiguous, in cvt_all segment order
    ushort* sr_b  = h_buf + (size_t)MROWS * FFN;
    ushort* plm_b = sr_b  + (size_t)MROWS * 128;
    ushort* Wq_b  = plm_b + (size_t)MROWS * PLM;
    ushort* Wk_b  = Wq_b  + (size_t)EMB * PLM;
    ushort* Wv_b  = Wk_b  + (size_t)EMB * 128;
    ushort* Wo_b  = Wv_b  + (size_t)EMB * 128;
    ushort* Wd_b  = Wo_b  + (size_t)PLM * EMB;
    ushort* Wu_b  = Wd_b  + (size_t)FFN * PLM;

    float* out_main = (float*)d_out;                        // [B*S, PLM]
    float* attn_out = out_main + (size_t)MROWS * PLM;       // [B,H,S,S]

    dim3 blk(256);

    // one fused conversion pass over all f32 inputs
    cvt_all<<<dim3(CV7 / 256), blk, 0, stream>>>(
        s_repre, plm, Wq, Wk, Wv, Wo, Wd, Wu, sr_b);

    // q = RoPE(plm @ Wq^T + bq)            -> [B,H,S,D]
    gemm_nt<1><<<dim3(MROWS / 64, EMB / 64), blk, 0, stream>>>(
        plm_b, Wq_b, bq, nullptr, nullptr, q_buf, MROWS, EMB, PLM);
    // k = RoPE(s_repre @ Wk^T + bk)        -> [B,H,S,D]
    gemm_nt<1><<<dim3(MROWS / 64, EMB / 64), blk, 0, stream>>>(
        sr_b, Wk_b, bk, nullptr, nullptr, k_buf, MROWS, EMB, 128);
    // v = s_repre @ Wv^T + bv              -> [B,H,D,S]
    gemm_nt<2><<<dim3(MROWS / 64, EMB / 64), blk, 0, stream>>>(
        sr_b, Wv_b, bv, nullptr, nullptr, v_buf, MROWS, EMB, 128);

    // attention probs (f32, to d_out) + vals (bf16)
    attn_kernel<<<dim3(SEQ / 16, BATCH * NH), blk, 0, stream>>>(
        q_buf, k_buf, v_buf, attn_out, vals);

    // x = vals @ Wo^T + bo + plm           -> x_buf (bf16)
    gemm_nt<3><<<dim3(MROWS / 64, PLM / 64), blk, 0, stream>>>(
        vals, Wo_b, bo, plm, nullptr, x_buf, MROWS, PLM, EMB);

    // resid = LayerNorm(x)
    ln_kernel<<<dim3(MROWS), blk, 0, stream>>>(x_buf, ln_g, ln_b, resid);

    // h = gelu(resid @ Wd^T + bd)
    gemm_nt<4><<<dim3(MROWS / 64, FFN / 64), blk, 0, stream>>>(
        resid, Wd_b, bd, nullptr, nullptr, h_buf, MROWS, FFN, PLM);

    // out = h @ Wu^T + bu + resid          -> d_out (f32)
    gemm_nt<5><<<dim3(MROWS / 64, PLM / 64), blk, 0, stream>>>(
        h_buf, Wu_b, bu, nullptr, resid, out_main, MROWS, PLM, FFN);
}

// Round 4
// 733.627 us; speedup vs baseline: 1.3114x; 1.0649x over previous
//
#include <hip/hip_runtime.h>
#include <hip/hip_bf16.h>
#include <math.h>

// Shapes (fixed by the problem)
#define BATCH 2
#define SEQ   2048
#define NH    12
#define HD    64
#define EMB   768      // NH*HD
#define PLM   1280
#define FFN   640
#define MROWS (BATCH*SEQ)   // 4096

typedef __attribute__((ext_vector_type(8))) short short8;   // 8 bf16
typedef __attribute__((ext_vector_type(4))) float floatx4;

#define MFMA16(a,b,c) __builtin_amdgcn_mfma_f32_16x16x32_bf16((a),(b),(c),0,0,0)

static __device__ __forceinline__ float b2f(ushort u) {
    return __uint_as_float(((unsigned)u) << 16);
}
static __device__ __forceinline__ ushort f2b(float f) {
    unsigned x = __float_as_uint(f);
    unsigned r = (x + 0x7fffu + ((x >> 16) & 1u)) >> 16;   // RNE, finite inputs
    return (ushort)r;
}
// packed f32x2 -> bf16x2 (v_cvt_pk_bf16_f32)
static __device__ __forceinline__ ushort2 f2b2(float a, float b) {
    __hip_bfloat162 h = __float22bfloat162_rn(make_float2(a, b));
    union { __hip_bfloat162 h2; ushort2 u2; } c; c.h2 = h;
    return c.u2;
}

// ---------------------------------------------------------------------------
// Fused f32 -> bf16 conversion for all 8 inputs (dsts contiguous in ws).
// ---------------------------------------------------------------------------
#define CV0 131072     // s_repre  (2*2048*128 /4)
#define CV1 1441792    // + plm    (2*2048*1280/4)
#define CV2 1687552    // + Wq     (768*1280/4)
#define CV3 1712128    // + Wk     (768*128/4)
#define CV4 1736704    // + Wv
#define CV5 1982464    // + Wo     (1280*768/4)
#define CV6 2187264    // + Wd     (640*1280/4)
#define CV7 2392064    // + Wu     (1280*640/4)

__global__ __launch_bounds__(256) void cvt_all(
    const float* __restrict__ s0, const float* __restrict__ s1,
    const float* __restrict__ s2, const float* __restrict__ s3,
    const float* __restrict__ s4, const float* __restrict__ s5,
    const float* __restrict__ s6, const float* __restrict__ s7,
    ushort* __restrict__ dst)
{
    int i = blockIdx.x * 256 + threadIdx.x;     // vec4 index
    const float* src; int start;
    if      (i < CV0) { src = s0; start = 0;   }
    else if (i < CV1) { src = s1; start = CV0; }
    else if (i < CV2) { src = s2; start = CV1; }
    else if (i < CV3) { src = s3; start = CV2; }
    else if (i < CV4) { src = s4; start = CV3; }
    else if (i < CV5) { src = s5; start = CV4; }
    else if (i < CV6) { src = s6; start = CV5; }
    else              { src = s7; start = CV6; }
    float4 v = ((const float4*)src)[i - start];
    ushort2 a = f2b2(v.x, v.y), b = f2b2(v.z, v.w);
    ushort4 o; o.x = a.x; o.y = a.y; o.z = b.x; o.w = b.y;
    ((ushort4*)dst)[i] = o;
}

// ---------------------------------------------------------------------------
// Stage one 64-row x 128-byte (64 bf16) tile from global into LDS via
// global_load_lds (width 16). LDS layout is linear [row][128B] with the
// T2 XOR-swizzle realized by PRE-SWIZZLING the global source column:
//   LDS[row*128 + c] = G[row][c ^ ((row&7)<<4)]
// ---------------------------------------------------------------------------
static __device__ __forceinline__ void stage_tile(
    const ushort* __restrict__ g,   // global tile base (row 0, k-col 0)
    int strideBytes,                // global row stride in bytes (K*2)
    int tid, ushort* lds)
{
    const int l   = tid & 63;
    const int w   = tid >> 6;
    const int sub = l >> 3;                             // row&7
    const int scol = (((l & 7) << 4) ^ (sub << 4));     // pre-swizzled col byte
#pragma unroll
    for (int s = 0; s < 2; ++s) {
        const int row = s * 32 + w * 8 + sub;
        const char* gp = (const char*)g + (size_t)row * strideBytes + scol;
        char* lp = (char*)lds + s * 4096 + w * 1024;    // wave-uniform base
        __builtin_amdgcn_global_load_lds(
            (const __attribute__((address_space(1))) void*)gp,
            (__attribute__((address_space(3))) void*)lp, 16, 0, 0);
    }
}

// ---------------------------------------------------------------------------
// NT GEMM (unchanged from round 2): 2-phase pipelined, double-buffered LDS,
// global_load_lds w16 with pre-swizzled source.
// ---------------------------------------------------------------------------
template<int EPI>
__global__ __launch_bounds__(256, 4) void gemm_nt(
    const ushort* __restrict__ A,      // [M,K] bf16
    const ushort* __restrict__ W,      // [N,K] bf16
    const float*  __restrict__ bias,   // [N]   f32
    const float*  __restrict__ residF, // [M,N] f32  (EPI==3)
    const ushort* __restrict__ residB, // [M,N] bf16 (EPI==5)
    void* __restrict__ out_,
    int M, int N, int K)
{
    __shared__ __align__(16) ushort As[2][64 * 64];
    __shared__ __align__(16) ushort Bs[2][64 * 64];

    const int tid  = threadIdx.x;
    const int wave = tid >> 6;
    const int lane = tid & 63;
    const int quad = lane >> 4;
    const int col  = lane & 15;
    const int m0   = blockIdx.x * 64 + wave * 16;
    const int n0   = blockIdx.y * 64;

    const int strideBytes = K * 2;
    const ushort* Ag = A + (size_t)(blockIdx.x * 64) * K;
    const ushort* Wg = W + (size_t)n0 * K;

    // swizzled frag-read byte offsets within a tile
    const int sw = (col & 7) << 4;
    const int a_off0 = (wave * 16 + col) * 128 + ((quad * 16) ^ sw);
    const int a_off1 = (wave * 16 + col) * 128 + ((64 + quad * 16) ^ sw);
    int b_off[8];
#pragma unroll
    for (int f = 0; f < 4; ++f) {
        int rb = (f * 16 + col) * 128;
        b_off[2 * f]     = rb + ((quad * 16) ^ sw);
        b_off[2 * f + 1] = rb + ((64 + quad * 16) ^ sw);
    }

    const floatx4 zero = {0.f, 0.f, 0.f, 0.f};
    floatx4 acc[4] = {zero, zero, zero, zero};

    // prologue: stage first K-tile
    stage_tile(Ag, strideBytes, tid, As[0]);
    stage_tile(Wg, strideBytes, tid, Bs[0]);
    __syncthreads();

    int buf = 0;
    for (int k0 = 0; k0 < K; k0 += 64) {
        if (k0 + 64 < K) {   // issue next-tile loads BEFORE compute (2-phase)
            stage_tile(Ag + (k0 + 64), strideBytes, tid, As[buf ^ 1]);
            stage_tile(Wg + (k0 + 64), strideBytes, tid, Bs[buf ^ 1]);
        }
        const char* Ab = (const char*)&As[buf][0];
        const char* Bb = (const char*)&Bs[buf][0];
        short8 a0 = *(const short8*)(Ab + a_off0);
        short8 a1 = *(const short8*)(Ab + a_off1);
        short8 b[8];
#pragma unroll
        for (int f = 0; f < 8; ++f) b[f] = *(const short8*)(Bb + b_off[f]);
#pragma unroll
        for (int f = 0; f < 4; ++f) {
            acc[f] = MFMA16(a0, b[2 * f], acc[f]);
            acc[f] = MFMA16(a1, b[2 * f + 1], acc[f]);
        }
        __syncthreads();
        buf ^= 1;
    }

    float bs[4];
#pragma unroll
    for (int f = 0; f < 4; ++f) bs[f] = bias[n0 + f * 16 + col];

    if constexpr (EPI == 1) {
        ushort* out = (ushort*)out_;
        const int h = n0 >> 6;
#pragma unroll
        for (int r = 0; r < 4; ++r) {
            int m = m0 + quad * 4 + r;
            int b_ = m >> 11, s = m & (SEQ - 1);
            size_t obase = ((size_t)(b_ * NH + h) * SEQ + s) * HD;
#pragma unroll
            for (int f = 0; f < 2; ++f) {
                int d = f * 16 + col;                 // 0..31
                float x1 = acc[f][r] + bs[f];
                float x2 = acc[f + 2][r] + bs[f + 2];
                float invf = __expf((float)d * -0.2878231366242557f); // 10000^(-d/32)
                float theta = (float)s * invf;
                float sn, cs;
                sincosf(theta, &sn, &cs);
                out[obase + d]      = f2b(x1 * cs - x2 * sn);
                out[obase + d + 32] = f2b(x2 * cs + x1 * sn);
            }
        }
    } else if constexpr (EPI == 2) {
        ushort (*tile)[72] = (ushort (*)[72])&As[0][0];
        ushort* out = (ushort*)out_;
        const int h = n0 >> 6;
        const int mi0 = wave * 16 + quad * 4;           // row within block tile
#pragma unroll
        for (int r = 0; r < 4; ++r)
#pragma unroll
            for (int f = 0; f < 4; ++f)
                tile[f * 16 + col][mi0 + r] = f2b(acc[f][r] + bs[f]);
        __syncthreads();
        const int mblk = blockIdx.x * 64;
        const int b_ = mblk >> 11, s0 = mblk & (SEQ - 1);
#pragma unroll
        for (int i = 0; i < 2; ++i) {
            int d = (tid >> 3) + i * 32;    // 0..63
            int c = (tid & 7) * 8;          // element offset along s
            short8 v = *(const short8*)&tile[d][c];
            *(short8*)&out[((size_t)((b_ * NH + h) * HD + d)) * SEQ + s0 + c] = v;
        }
    } else if constexpr (EPI == 3) {
        ushort* out = (ushort*)out_;
#pragma unroll
        for (int r = 0; r < 4; ++r) {
            int m = m0 + quad * 4 + r;
#pragma unroll
            for (int f = 0; f < 4; ++f) {
                size_t idx = (size_t)m * N + n0 + f * 16 + col;
                out[idx] = f2b(acc[f][r] + bs[f] + residF[idx]);
            }
        }
    } else if constexpr (EPI == 4) {
        ushort* out = (ushort*)out_;
#pragma unroll
        for (int r = 0; r < 4; ++r) {
            int m = m0 + quad * 4 + r;
#pragma unroll
            for (int f = 0; f < 4; ++f) {
                size_t idx = (size_t)m * N + n0 + f * 16 + col;
                float y = acc[f][r] + bs[f];
                out[idx] = f2b(0.5f * y * (1.0f + erff(y * 0.70710678118654752f)));
            }
        }
    } else {
        float* out = (float*)out_;
#pragma unroll
        for (int r = 0; r < 4; ++r) {
            int m = m0 + quad * 4 + r;
#pragma unroll
            for (int f = 0; f < 4; ++f) {
                size_t idx = (size_t)m * N + n0 + f * 16 + col;
                out[idx] = acc[f][r] + bs[f] + b2f(residB[idx]);
            }
        }
    }
}

// ---------------------------------------------------------------------------
// Attention v3: SINGLE pass + LDS-buffered E tile + streaming epilogue.
//   Block = (qt, bh): 16 q-rows; wave w owns kv [512w, 512w+512).
//   Per ch (64 kv): QK MFMA once -> e = exp(S/8) (UNNORMALIZED) -> bf16 into
//   persistent Eb[16][2048] (row stride 2056: +8 elem pad -> 2-way banks);
//   f32 row-sums accumulate in regs; PV MFMA reads A-frags straight from Eb
//   (ds_read_b128) and accumulates UNNORMALIZED (rinv factors out linearly).
//   NO global stores in the compute loop (stores no longer pollute vmcnt
//   waits before load-consuming MFMAs).
//   Row-sums -> Eb row pad (16 B/row = 4 waves x f32). Epilogue: pure
//   streaming write of attn_out = bf16(e)*rinv, 1-2 KB contiguous bursts,
//   sequential rows (DRAM-page friendly). Then vals reduce (scratch = Eb).
// LDS 65792 B -> 2 blocks/CU.
// ---------------------------------------------------------------------------
#define EBS 2056            // Eb row stride in bf16 elements (4112 B)

__global__ __launch_bounds__(256, 2) void attn_kernel(
    const ushort* __restrict__ qb, const ushort* __restrict__ kb,
    const ushort* __restrict__ vb,
    float* __restrict__ attn_out,    // [B,H,S,S] f32
    ushort* __restrict__ vals)       // [B*S, EMB] bf16
{
    const int qt   = blockIdx.x;     // 0..127 (16 q-rows)
    const int bh   = blockIdx.y;     // 0..23
    const int tid  = threadIdx.x;
    const int wave = tid >> 6;
    const int lane = tid & 63;
    const int quad = lane >> 4;
    const int col  = lane & 15;
    const int kv0  = wave * 512;
    const int qrow0 = qt * 16;

    __shared__ __align__(16) ushort Eb[16 * EBS];   // 65792 B

    const floatx4 zero = {0.f, 0.f, 0.f, 0.f};

    // Q fragments for the block's 16 rows (same for all waves; L1-served)
    const ushort* qrow = qb + ((size_t)bh * SEQ + qrow0 + col) * HD + quad * 8;
    short8 aq0 = *(const short8*)qrow;
    short8 aq1 = *(const short8*)(qrow + 32);

    const ushort* kbase = kb + (size_t)bh * SEQ * HD + (size_t)(kv0 + col) * HD + quad * 8;
    const ushort* vbase = vb + (size_t)bh * HD * SEQ + (size_t)col * SEQ + kv0 + quad * 8;

    // ---- single pass: QK -> e -> Eb (bf16) ; sums ; PV (unnormalized) ----
    float sums[4] = {0.f, 0.f, 0.f, 0.f};
    floatx4 acco[4] = {zero, zero, zero, zero};

    for (int ch = 0; ch < 8; ++ch) {
        const int kvc = kv0 + ch * 64;          // global kv base of this chunk
#pragma unroll
        for (int f = 0; f < 4; ++f) {
            const ushort* kr = kbase + (size_t)(ch * 64 + f * 16) * HD;
            short8 b0 = *(const short8*)kr;
            short8 b1 = *(const short8*)(kr + 32);
            floatx4 t = MFMA16(aq0, b0, zero);
            t = MFMA16(aq1, b1, t);
            float e0 = __expf(t[0] * 0.125f);
            float e1 = __expf(t[1] * 0.125f);
            float e2 = __expf(t[2] * 0.125f);
            float e3 = __expf(t[3] * 0.125f);
            sums[0] += e0; sums[1] += e1; sums[2] += e2; sums[3] += e3;
            ushort2 p01 = f2b2(e0, e1), p23 = f2b2(e2, e3);
            const int cb = kvc + f * 16 + col;  // column in Eb
            Eb[(quad * 4 + 0) * EBS + cb] = p01.x;
            Eb[(quad * 4 + 1) * EBS + cb] = p01.y;
            Eb[(quad * 4 + 2) * EBS + cb] = p23.x;
            Eb[(quad * 4 + 3) * EBS + cb] = p23.y;
        }
        // PV: A-frags straight from Eb (row=col, k-slice quad*8)
        const ushort* pl = &Eb[col * EBS + kvc + quad * 8];
        short8 ap0 = *(const short8*)pl;
        short8 ap1 = *(const short8*)(pl + 32);
#pragma unroll
        for (int f = 0; f < 4; ++f) {
            const ushort* vr = vbase + (size_t)(f * 16) * SEQ + ch * 64;
            short8 b0 = *(const short8*)vr;
            short8 b1 = *(const short8*)(vr + 32);
            acco[f] = MFMA16(ap0, b0, acco[f]);
            acco[f] = MFMA16(ap1, b1, acco[f]);
        }
    }

    // ---- cross-lane partial row sums, park in Eb row pad [row][2048+wave] ----
#pragma unroll
    for (int r = 0; r < 4; ++r) {
        float v = sums[r];
        v += __shfl_xor(v, 1); v += __shfl_xor(v, 2);
        v += __shfl_xor(v, 4); v += __shfl_xor(v, 8);
        sums[r] = v;
    }
    if (col == 0) {
#pragma unroll
        for (int r = 0; r < 4; ++r)
            *(float*)((char*)Eb + (quad * 4 + r) * (EBS * 2) + 4096 + wave * 4) = sums[r];
    }
    __syncthreads();   // Eb (E + pads) complete, visible block-wide

    // ---- epilogue A: streaming attn_out write, wave w -> rows 4w..4w+3 ----
    const size_t gbase = (size_t)bh * SEQ + qrow0;
#pragma unroll
    for (int rr = 0; rr < 4; ++rr) {
        const int row = wave * 4 + rr;
        float4 ps = *(const float4*)((char*)Eb + row * (EBS * 2) + 4096);
        float rinv = 1.0f / (ps.x + ps.y + ps.z + ps.w);
        float* orow = attn_out + (gbase + row) * SEQ;
#pragma unroll
        for (int it = 0; it < 4; ++it) {
            const ushort* src = &Eb[row * EBS + it * 512 + lane * 8];
            short8 ev = *(const short8*)src;
            float4 o0, o1;
            o0.x = b2f((ushort)ev[0]) * rinv; o0.y = b2f((ushort)ev[1]) * rinv;
            o0.z = b2f((ushort)ev[2]) * rinv; o0.w = b2f((ushort)ev[3]) * rinv;
            o1.x = b2f((ushort)ev[4]) * rinv; o1.y = b2f((ushort)ev[5]) * rinv;
            o1.z = b2f((ushort)ev[6]) * rinv; o1.w = b2f((ushort)ev[7]) * rinv;
            float* dst = orow + it * 512 + lane * 8;
            *(float4*)dst = o0;
            *(float4*)(dst + 4) = o1;
        }
    }

    // ---- normalize acco by this lane's row inverses ----
    {
        float4 ps0 = *(const float4*)((char*)Eb + (quad * 4 + 0) * (EBS * 2) + 4096);
        float4 ps1 = *(const float4*)((char*)Eb + (quad * 4 + 1) * (EBS * 2) + 4096);
        float4 ps2 = *(const float4*)((char*)Eb + (quad * 4 + 2) * (EBS * 2) + 4096);
        float4 ps3 = *(const float4*)((char*)Eb + (quad * 4 + 3) * (EBS * 2) + 4096);
        float ri0 = 1.0f / (ps0.x + ps0.y + ps0.z + ps0.w);
        float ri1 = 1.0f / (ps1.x + ps1.y + ps1.z + ps1.w);
        float ri2 = 1.0f / (ps2.x + ps2.y + ps2.z + ps2.w);
        float ri3 = 1.0f / (ps3.x + ps3.y + ps3.z + ps3.w);
#pragma unroll
        for (int f = 0; f < 4; ++f) {
            acco[f][0] *= ri0; acco[f][1] *= ri1;
            acco[f][2] *= ri2; acco[f][3] *= ri3;
        }
    }

    // ---- cross-wave PV reduction: scratch = Eb reinterpreted as f32 ----
    __syncthreads();   // all reads of Eb (E + pads) done; safe to overwrite
    float* scr = (float*)Eb;     // [4 waves][16 rows * 68]
#pragma unroll
    for (int f = 0; f < 4; ++f)
#pragma unroll
        for (int r = 0; r < 4; ++r)
            scr[wave * 16 * 68 + (quad * 4 + r) * 68 + f * 16 + col] = acco[f][r];
    __syncthreads();

    {
        int row = tid >> 4;            // 0..15
        int d0  = (tid & 15) * 4;      // 0..60
        int off = row * 68 + d0;
        float4 s0 = *(const float4*)&scr[0 * 16 * 68 + off];
        float4 s1 = *(const float4*)&scr[1 * 16 * 68 + off];
        float4 s2 = *(const float4*)&scr[2 * 16 * 68 + off];
        float4 s3 = *(const float4*)&scr[3 * 16 * 68 + off];
        float4 s;
        s.x = s0.x + s1.x + s2.x + s3.x;
        s.y = s0.y + s1.y + s2.y + s3.y;
        s.z = s0.z + s1.z + s2.z + s3.z;
        s.w = s0.w + s1.w + s2.w + s3.w;
        ushort2 u0 = f2b2(s.x, s.y), u1 = f2b2(s.z, s.w);
        ushort4 o; o.x = u0.x; o.y = u0.y; o.z = u1.x; o.w = u1.y;
        const int b = bh / NH, h = bh - b * NH;
        size_t idx = ((size_t)(b * SEQ + qrow0 + row)) * EMB + h * HD + d0;
        *(ushort4*)&vals[idx] = o;
    }
}

// ---------------------------------------------------------------------------
// LayerNorm over 1280, one block (256 threads) per row.
// ---------------------------------------------------------------------------
__global__ __launch_bounds__(256) void ln_kernel(
    const ushort* __restrict__ x, const float* __restrict__ g,
    const float* __restrict__ bt, ushort* __restrict__ out)
{
    const int row = blockIdx.x;
    const int tid = threadIdx.x;
    const ushort* xr = x + (size_t)row * PLM;

    float xs[5];
    float s = 0.f, s2 = 0.f;
#pragma unroll
    for (int i = 0; i < 5; ++i) {
        float v = b2f(xr[tid + i * 256]);
        xs[i] = v; s += v; s2 += v * v;
    }
#pragma unroll
    for (int off = 1; off < 64; off <<= 1) {
        s  += __shfl_xor(s,  off);
        s2 += __shfl_xor(s2, off);
    }
    __shared__ float red[8];
    const int wave = tid >> 6, lane = tid & 63;
    if (lane == 0) { red[wave] = s; red[4 + wave] = s2; }
    __syncthreads();
    s  = red[0] + red[1] + red[2] + red[3];
    s2 = red[4] + red[5] + red[6] + red[7];
    float mean = s * (1.0f / PLM);
    float var  = s2 * (1.0f / PLM) - mean * mean;
    float rstd = rsqrtf(var + 1e-5f);

    ushort* orow = out + (size_t)row * PLM;
#pragma unroll
    for (int i = 0; i < 5; ++i) {
        int c = tid + i * 256;
        orow[c] = f2b((xs[i] - mean) * rstd * g[c] + bt[c]);
    }
}

// ---------------------------------------------------------------------------
extern "C" void kernel_launch(void* const* d_in, const int* in_sizes, int n_in,
                              void* d_out, int out_size, void* d_ws, size_t ws_size,
                              hipStream_t stream)
{
    const float* s_repre = (const float*)d_in[0];
    const float* plm     = (const float*)d_in[1];
    const float* Wq = (const float*)d_in[2];
    const float* bq = (const float*)d_in[3];
    const float* Wk = (const float*)d_in[4];
    const float* bk = (const float*)d_in[5];
    const float* Wv = (const float*)d_in[6];
    const float* bv = (const float*)d_in[7];
    const float* Wo = (const float*)d_in[8];
    const float* bo = (const float*)d_in[9];
    const float* ln_g = (const float*)d_in[10];
    const float* ln_b = (const float*)d_in[11];
    const float* Wd = (const float*)d_in[12];
    const float* bd = (const float*)d_in[13];
    const float* Wu = (const float*)d_in[14];
    const float* bu = (const float*)d_in[15];

    // workspace layout (bf16 elements)
    ushort* ws    = (ushort*)d_ws;
    ushort* q_buf = ws;                          // [B,H,S,D]
    ushort* k_buf = q_buf + (size_t)MROWS * EMB;
    ushort* v_buf = k_buf + (size_t)MROWS * EMB; // [B,H,D,S]
    ushort* vals  = v_buf + (size_t)MROWS * EMB; // [B*S, EMB]
    ushort* x_buf = vals  + (size_t)MROWS * EMB; // [B*S, PLM]
    ushort* resid = x_buf + (size_t)MROWS * PLM; // [B*S, PLM]
    ushort* h_buf = resid + (size_t)MROWS * PLM; // [B*S, FFN]
    // bf16 copies of f32 inputs — contiguous, in cvt_all segment order
    ushort* sr_b  = h_buf + (size_t)MROWS * FFN;
    ushort* plm_b = sr_b  + (size_t)MROWS * 128;
    ushort* Wq_b  = plm_b + (size_t)MROWS * PLM;
    ushort* Wk_b  = Wq_b  + (size_t)EMB * PLM;
    ushort* Wv_b  = Wk_b  + (size_t)EMB * 128;
    ushort* Wo_b  = Wv_b  + (size_t)EMB * 128;
    ushort* Wd_b  = Wo_b  + (size_t)PLM * EMB;
    ushort* Wu_b  = Wd_b  + (size_t)FFN * PLM;

    float* out_main = (float*)d_out;                        // [B*S, PLM]
    float* attn_out = out_main + (size_t)MROWS * PLM;       // [B,H,S,S]

    dim3 blk(256);

    // one fused conversion pass over all f32 inputs
    cvt_all<<<dim3(CV7 / 256), blk, 0, stream>>>(
        s_repre, plm, Wq, Wk, Wv, Wo, Wd, Wu, sr_b);

    // q = RoPE(plm @ Wq^T + bq)            -> [B,H,S,D]
    gemm_nt<1><<<dim3(MROWS / 64, EMB / 64), blk, 0, stream>>>(
        plm_b, Wq_b, bq, nullptr, nullptr, q_buf, MROWS, EMB, PLM);
    // k = RoPE(s_repre @ Wk^T + bk)        -> [B,H,S,D]
    gemm_nt<1><<<dim3(MROWS / 64, EMB / 64), blk, 0, stream>>>(
        sr_b, Wk_b, bk, nullptr, nullptr, k_buf, MROWS, EMB, 128);
    // v = s_repre @ Wv^T + bv              -> [B,H,D,S]
    gemm_nt<2><<<dim3(MROWS / 64, EMB / 64), blk, 0, stream>>>(
        sr_b, Wv_b, bv, nullptr, nullptr, v_buf, MROWS, EMB, 128);

    // attention probs (f32, to d_out) + vals (bf16)
    attn_kernel<<<dim3(SEQ / 16, BATCH * NH), blk, 0, stream>>>(
        q_buf, k_buf, v_buf, attn_out, vals);

    // x = vals @ Wo^T + bo + plm           -> x_buf (bf16)
    gemm_nt<3><<<dim3(MROWS / 64, PLM / 64), blk, 0, stream>>>(
        vals, Wo_b, bo, plm, nullptr, x_buf, MROWS, PLM, EMB);

    // resid = LayerNorm(x)
    ln_kernel<<<dim3(MROWS), blk, 0, stream>>>(x_buf, ln_g, ln_b, resid);

    // h = gelu(resid @ Wd^T + bd)
    gemm_nt<4><<<dim3(MROWS / 64, FFN / 64), blk, 0, stream>>>(
        resid, Wd_b, bd, nullptr, nullptr, h_buf, MROWS, FFN, PLM);

    // out = h @ Wu^T + bu + resid          -> d_out (f32)
    gemm_nt<5><<<dim3(MROWS / 64, PLM / 64), blk, 0, stream>>>(
        h_buf, Wu_b, bu, nullptr, resid, out_main, MROWS, PLM, FFN);
}